// Round 6
// baseline (185.629 us; speedup 1.0000x reference)
//
#include <hip/hip_runtime.h>
#include <math.h>

// Problem constants
constexpr int Bn   = 32;
constexpr int L    = 65536;            // T*K
constexpr int NCH  = 6;
constexpr int SPAN = 256;              // hexads (l-steps) per wave-span
constexpr int NS   = L / SPAN;         // 256 spans per batch row
constexpr int NIT  = SPAN / 64;        // 4 blocks of 64 per span
constexpr int ROW  = L * NCH;          // floats per row (imu/mn/out)
constexpr int EPW_ROW = (L - 1) * NCH; // floats per row (eps_walk)
constexpr int NWAVE = Bn * NS;         // 8192 wave-spans
constexpr int HTILE = 768;             // half-span tile: 128 hexads = 768 floats
constexpr float AF = 0.99999f;         // a = 1 - theta*dt (fp32, matches ref)
constexpr float DS_ACC  = 0.2f   * 0.004472135954999579f; // std*sqrt(2*theta*dt)
constexpr float DS_GYRO = 0.015f * 0.004472135954999579f;

// native clang vectors (HIP float2/float4 are class types -> nontemporal
// builtins reject them)
typedef float vf2 __attribute__((ext_vector_type(2)));
typedef float vf4 __attribute__((ext_vector_type(4)));

// a^(lane+1) and a^(63-lane), double-accurate, computed once per thread
__device__ __forceinline__ void lane_pows(int lane, float& ap1, float& arev) {
    const double a = (double)AF;
    double t = a, p1 = 1.0, pr = 1.0;
    int e1 = lane + 1, er = 63 - lane;
    #pragma unroll
    for (int k = 0; k < 7; ++k) {
        if (e1 & (1 << k)) p1 *= t;
        if (er & (1 << k)) pr *= t;
        t *= t;
    }
    ap1 = (float)p1; arev = (float)pr;
}

__device__ __forceinline__ float a_pow64() {
    double t = (double)AF;
    #pragma unroll
    for (int k = 0; k < 6; ++k) t *= t;   // a^64
    return (float)t;
}

// Stage HALF of a wave-span's epw window (384 floats of payload x2 halves)
// into the wave-private half-tile: 6 contiguous coalesced vf2 loads/lane.
// Tile float f (local) <-> epw row float 6*(l0-1) + 768*h + f.
// s==0,h==0: idx<0 clamped (garbage lands in the l==0 slot; seed overwrites).
__device__ __forceinline__ void stage_epw_half(const float* __restrict__ rowp,
                                               float* __restrict__ lw,
                                               int l0, int h) {
    int lane = threadIdx.x & 63;
    int base = 6 * l0 - 6 + HTILE * h;
    #pragma unroll
    for (int k = 0; k < 6; ++k) {
        int idx = base + 2 * (k * 64 + lane);
        int cidx = idx < 0 ? 0 : idx;     // s==0 guard (seed overwrites)
        vf2 v = *(const vf2*)(rowp + cidx);
        *(vf2*)(lw + 2 * (k * 64 + lane)) = v;
    }
}

// read hexad for local block-step it2 (global it = 2h+it2) from half-tile
__device__ __forceinline__ void read_x_half(const float* __restrict__ lw,
                                            const float* __restrict__ eps0,
                                            int b, int l0, int h, int it2,
                                            float x[6]) {
    int lane = threadIdx.x & 63;
    int off = 6 * (it2 * 64 + lane);      // local offset within half-tile
    vf2 v0 = *(const vf2*)(lw + off);
    vf2 v1 = *(const vf2*)(lw + off + 2);
    vf2 v2 = *(const vf2*)(lw + off + 4);
    x[0] = v0.x * DS_ACC;  x[1] = v0.y * DS_ACC;  x[2] = v1.x * DS_ACC;
    x[3] = v1.y * DS_GYRO; x[4] = v2.x * DS_GYRO; x[5] = v2.y * DS_GYRO;
    if (l0 + (2 * h + it2) * 64 + lane == 0) {    // bias0 seed = eps0*std0
        const float* e0 = eps0 + b * NCH;
        x[0] = e0[0] * 0.2f;   x[1] = e0[1] * 0.2f;   x[2] = e0[2] * 0.2f;
        x[3] = e0[3] * 0.015f; x[4] = e0[4] * 0.015f; x[5] = e0[5] * 0.015f;
    }
}

// ---------- K1: per-span weighted aggregates ----------
// P_s = sum_t a^(63-t) * [ Horner over it with A64 of x(it,t) ]
// Half-tile staging keeps LDS at 12KB/block; (256,8) caps VGPR at 64 ->
// 32 waves/CU for max TLP on this pure-read kernel.
__global__ __launch_bounds__(256, 8) void k_partials(
    const float* __restrict__ eps0,
    const float* __restrict__ epw,
    float* __restrict__ part)
{
    __shared__ float lds[4 * HTILE];               // 12 KB
    int lane = threadIdx.x & 63;
    int wv   = threadIdx.x >> 6;
    int w = blockIdx.x * 4 + wv;
    int b = w / NS, s = w % NS;
    int l0 = s * SPAN;
    float* lw = lds + wv * HTILE;

    float ap1, arev; lane_pows(lane, ap1, arev);
    const float A64 = a_pow64();
    const float* rowp = epw + (size_t)b * EPW_ROW;

    float acc[6];
    #pragma unroll
    for (int h = 0; h < 2; ++h) {
        stage_epw_half(rowp, lw, l0, h);           // coalesced; warms L3 for K3
        #pragma unroll
        for (int it2 = 0; it2 < 2; ++it2) {
            float x[6]; read_x_half(lw, eps0, b, l0, h, it2, x);
            #pragma unroll
            for (int c = 0; c < 6; ++c)
                acc[c] = (h == 0 && it2 == 0) ? x[c] : fmaf(A64, acc[c], x[c]);
        }
    }

    float v[6];
    #pragma unroll
    for (int c = 0; c < 6; ++c) v[c] = arev * acc[c];
    #pragma unroll
    for (int c = 0; c < 6; ++c) {
        #pragma unroll
        for (int m = 1; m < 64; m <<= 1) v[c] += __shfl_xor(v[c], m, 64);
    }

    if (lane < 6) {
        float r = v[0];
        if (lane == 1) r = v[1]; else if (lane == 2) r = v[2];
        else if (lane == 3) r = v[3]; else if (lane == 4) r = v[4];
        else if (lane == 5) r = v[5];
        part[(size_t)w * NCH + lane] = r;
    }
}

// ---------- K2: scan span aggregates per chain (tiny, double) ----------
__global__ __launch_bounds__(64) void k_scan(
    const float* __restrict__ part,
    float* __restrict__ carry)
{
    int lane = threadIdx.x;
    int chain = blockIdx.x;              // b*6 + c
    int b = chain / NCH, c = chain % NCH;

    double a = (double)AF;
    double A = a;
    #pragma unroll
    for (int k = 0; k < 8; ++k) A *= A;  // a^256 = a^SPAN
    double A4 = A * A; A4 *= A4;         // A^4 (per-lane span of 4 segments)

    int s0 = lane * 4;
    size_t base = (size_t)b * NS * NCH + c;
    float pv[4];
    #pragma unroll
    for (int k = 0; k < 4; ++k) pv[k] = part[base + (size_t)(s0 + k) * NCH];

    double t = 0.0;
    #pragma unroll
    for (int k = 0; k < 4; ++k) t = A * t + (double)pv[k];

    double I = t, m = A4;
    #pragma unroll
    for (int d = 1; d <= 32; d <<= 1) {
        double up = __shfl_up(I, d, 64);
        if (lane >= d) I = m * up + I;
        m = m * m;
    }
    double cin = __shfl_up(I, 1, 64);
    if (lane == 0) cin = 0.0;

    double e = cin;
    #pragma unroll
    for (int k = 0; k < 4; ++k) {
        carry[base + (size_t)(s0 + k) * NCH] = (float)e;  // E_{s-1}
        e = A * e + (double)pv[k];
    }
}

// ---------- K3: fused scan + elementwise, HALF-SPAN passes ----------
// Two passes of {stage epw half, load imu/mn half (nt f4), KS on 12 chains,
// carry fixup, bias->tile, f4 read, combine, nt store}. Halves couple only
// through the scalar carry e[6]. Working set per pass ~60 VGPR + 3KB LDS
// -> (256,6): 24 waves/CU (was 16), same traffic, +50% TLP.
// All LDS reuse is same-wave: in-order DS pipe, no barriers needed.
__global__ __launch_bounds__(256, 6) void k_apply(
    const float* __restrict__ imu,
    const float* __restrict__ eps0,
    const float* __restrict__ epw,
    const float* __restrict__ mn,
    const float* __restrict__ carry,
    float* __restrict__ out)
{
    __shared__ float lds[4 * HTILE];               // 12 KB
    int lane = threadIdx.x & 63;
    int wv   = threadIdx.x >> 6;
    int w = blockIdx.x * 4 + wv;
    int b = w / NS, s = w % NS;
    int l0 = s * SPAN;
    float* lw = lds + wv * HTILE;

    float e[6];
    #pragma unroll
    for (int c = 0; c < 6; ++c) e[c] = carry[(size_t)w * NCH + c];

    float ap1, arev; lane_pows(lane, ap1, arev);
    const float A64 = a_pow64();
    const float inv   = 1.0f / 65535.0f;
    const float twopi = 6.283185307179586f;
    const float* rowp = epw + (size_t)b * EPW_ROW;
    size_t fbase = (size_t)b * ROW + (size_t)l0 * NCH;
    const vf4* ip = (const vf4*)(imu + fbase);
    const vf4* mp = (const vf4*)(mn + fbase);
    vf4* op = (vf4*)(out + fbase);
    int lane3 = lane % 3;

    #pragma unroll
    for (int h = 0; h < 2; ++h) {
        // stage epw half (cached loads; L3-resident from K1)
        stage_epw_half(rowp, lw, l0, h);

        // imu/mn nt float4 loads for this half (q = 3h .. 3h+2)
        vf4 iv[3], mv[3];
        #pragma unroll
        for (int q2 = 0; q2 < 3; ++q2) {
            int qg = 3 * h + q2;
            iv[q2] = __builtin_nontemporal_load(ip + qg * 64 + lane);
            mv[q2] = __builtin_nontemporal_load(mp + qg * 64 + lane);
        }

        // temp curve for this half's two block-steps
        float ta[2], tg[2];
        #pragma unroll
        for (int it2 = 0; it2 < 2; ++it2) {
            int l = l0 + (2 * h + it2) * 64 + lane;
            float tt = (float)l * inv;
            float temp = fmaf(5.0f, __sinf(twopi * tt), fmaf(2.0f, tt, 20.0f));
            ta[it2] = temp * 0.001f; tg[it2] = temp * 0.01f;
        }

        // x from half-tile, 12 independent Kogge-Stone chains
        float x[2][6];
        #pragma unroll
        for (int it2 = 0; it2 < 2; ++it2)
            read_x_half(lw, eps0, b, l0, h, it2, x[it2]);

        float m = AF;
        #pragma unroll
        for (int d = 1; d < 64; d <<= 1) {
            #pragma unroll
            for (int it2 = 0; it2 < 2; ++it2) {
                #pragma unroll
                for (int c = 0; c < 6; ++c) {
                    float up = __shfl_up(x[it2][c], d, 64);
                    if (lane >= d) x[it2][c] = fmaf(m, up, x[it2][c]);
                }
            }
            m *= m;
        }

        // carry fixup (e persists across halves) + fold temp term
        #pragma unroll
        for (int c = 0; c < 6; ++c) {
            float ec = e[c];
            #pragma unroll
            for (int it2 = 0; it2 < 2; ++it2) {
                float z = __shfl(x[it2][c], 63, 64);
                float t = (c < 3) ? ta[it2] : tg[it2];
                x[it2][c] = fmaf(ap1, ec, x[it2][c]) + t;   // bias + temp
                ec = fmaf(A64, ec, z);
            }
            e[c] = ec;
        }

        // overwrite half-tile with bias hexads (x-reads above already done)
        #pragma unroll
        for (int it2 = 0; it2 < 2; ++it2) {
            vf2* d = (vf2*)(lw + it2 * 384 + lane * 6);
            vf2 a0 = {x[it2][0], x[it2][1]};
            vf2 a1 = {x[it2][2], x[it2][3]};
            vf2 a2 = {x[it2][4], x[it2][5]};
            d[0] = a0; d[1] = a1; d[2] = a2;
        }

        // read half-tile as float4, combine, full-line nt stores.
        // channel pattern of global float4 qg: r=(lane%3 + qg%3)%3, and
        // qg%3 == q2 (qg = 3h+q2), so the pattern is h-independent.
        const vf4* lr = (const vf4*)lw;
        #pragma unroll
        for (int q2 = 0; q2 < 3; ++q2) {
            int qg = 3 * h + q2;
            vf4 v = lr[q2 * 64 + lane];       // lgkmcnt-ordered vs bias writes
            int r = lane3 + q2; if (r >= 3) r -= 3;
            vf4 ns = (r == 0) ? (vf4){0.1f, 0.1f, 0.1f, 0.01f}
                   : (r == 1) ? (vf4){0.01f, 0.01f, 0.1f, 0.1f}
                              : (vf4){0.1f, 0.01f, 0.01f, 0.01f};
            vf4 o = iv[q2] + v + mv[q2] * ns;
            __builtin_nontemporal_store(o, op + qg * 64 + lane);
        }
    }
}

extern "C" void kernel_launch(void* const* d_in, const int* in_sizes, int n_in,
                              void* d_out, int out_size, void* d_ws, size_t ws_size,
                              hipStream_t stream) {
    const float* imu  = (const float*)d_in[0];   // [B, L, 6]
    const float* eps0 = (const float*)d_in[1];   // [B, 6]
    const float* epw  = (const float*)d_in[2];   // [B, L-1, 6]
    const float* mn   = (const float*)d_in[3];   // [B, L, 6]
    float* out = (float*)d_out;

    float* part  = (float*)d_ws;                 // NWAVE*6 floats
    float* carry = part + (size_t)NWAVE * NCH;   // NWAVE*6 floats

    k_partials<<<NWAVE / 4, 256, 0, stream>>>(eps0, epw, part);
    k_scan<<<Bn * NCH, 64, 0, stream>>>(part, carry);
    k_apply<<<NWAVE / 4, 256, 0, stream>>>(imu, eps0, epw, mn, carry, out);
}

// Round 8
// 179.321 us; speedup vs baseline: 1.0352x; 1.0352x over previous
//
#include <hip/hip_runtime.h>
#include <math.h>

// Problem constants
constexpr int Bn   = 32;
constexpr int L    = 65536;            // T*K
constexpr int NCH  = 6;
constexpr int SPAN = 256;              // hexads (l-steps) per wave-span
constexpr int NS   = L / SPAN;         // 256 spans per batch row
constexpr int NIT  = SPAN / 64;        // 4 blocks of 64 per span
constexpr int ROW  = L * NCH;          // floats per row (imu/mn/out)
constexpr int EPW_ROW = (L - 1) * NCH; // floats per row (eps_walk)
constexpr int NWAVE = Bn * NS;         // 8192 wave-spans
constexpr int TILE = SPAN * NCH;       // 1536 floats per wave tile
constexpr float AF = 0.99999f;         // a = 1 - theta*dt (fp32, matches ref)
constexpr float DS_ACC  = 0.2f   * 0.004472135954999579f; // std*sqrt(2*theta*dt)
constexpr float DS_GYRO = 0.015f * 0.004472135954999579f;

// native clang vectors (HIP float2/float4 are class types -> nontemporal
// builtins reject them)
typedef float vf2 __attribute__((ext_vector_type(2)));
typedef float vf4 __attribute__((ext_vector_type(4)));

// a^(lane+1) and a^(63-lane), double-accurate, computed once per thread
__device__ __forceinline__ void lane_pows(int lane, float& ap1, float& arev) {
    const double a = (double)AF;
    double t = a, p1 = 1.0, pr = 1.0;
    int e1 = lane + 1, er = 63 - lane;
    #pragma unroll
    for (int k = 0; k < 7; ++k) {
        if (e1 & (1 << k)) p1 *= t;
        if (er & (1 << k)) pr *= t;
        t *= t;
    }
    ap1 = (float)p1; arev = (float)pr;
}

__device__ __forceinline__ float a_pow64() {
    double t = (double)AF;
    #pragma unroll
    for (int k = 0; k < 6; ++k) t *= t;   // a^64
    return (float)t;
}

// a^e for 0<=e<512, double repeated-squaring (init-time only)
__device__ __forceinline__ double apow(int e) {
    double t = (double)AF, p = 1.0;
    #pragma unroll
    for (int k = 0; k < 9; ++k) {
        if (e & (1 << k)) p *= t;
        t *= t;
    }
    return p;
}

// Stage this wave-span's epw window into the wave-private LDS tile.
// Window = floats [6*(l0-1), 6*(l0-1)+1536) = 768 vf2 = 12 contiguous
// coalesced vf2 loads per lane. Tile float f <-> epw row float 6*(l0-1)+f,
// so hexad for step l sits at tile offset 6*(l-l0). s==0: idx<0 clamped
// (garbage lands in the l==0 slot, which the eps0 seed overwrites).
__device__ __forceinline__ void stage_epw(const float* __restrict__ rowp,
                                          float* __restrict__ lw,
                                          int l0) {
    int lane = threadIdx.x & 63;
    int base = 6 * l0 - 6;
    #pragma unroll
    for (int k = 0; k < 12; ++k) {
        int idx = base + 2 * (k * 64 + lane);
        int cidx = idx < 0 ? 0 : idx;     // s==0 guard (seed overwrites)
        vf2 v = *(const vf2*)(rowp + cidx);
        *(vf2*)(lw + 2 * (k * 64 + lane)) = v;
    }
}

// read hexad for block-step (it,lane) from the tile, apply diff scales + seed
__device__ __forceinline__ void read_x(const float* __restrict__ lw,
                                       const float* __restrict__ eps0,
                                       int b, int l0, int it, float x[6]) {
    int lane = threadIdx.x & 63;
    int off = 6 * (it * 64 + lane);
    vf2 v0 = *(const vf2*)(lw + off);
    vf2 v1 = *(const vf2*)(lw + off + 2);
    vf2 v2 = *(const vf2*)(lw + off + 4);
    x[0] = v0.x * DS_ACC;  x[1] = v0.y * DS_ACC;  x[2] = v1.x * DS_ACC;
    x[3] = v1.y * DS_GYRO; x[4] = v2.x * DS_GYRO; x[5] = v2.y * DS_GYRO;
    if (l0 + it * 64 + lane == 0) {       // bias0 seed = eps0*std0
        const float* e0 = eps0 + b * NCH;
        x[0] = e0[0] * 0.2f;   x[1] = e0[1] * 0.2f;   x[2] = e0[2] * 0.2f;
        x[3] = e0[3] * 0.015f; x[4] = e0[4] * 0.015f; x[5] = e0[5] * 0.015f;
    }
}

// ---------- K1: per-span weighted aggregates, STREAMING (no LDS) ----------
// P_c = sum_{j<256} a^(255-j) x[j,c]. Computed directly in epw streaming
// order: lane's k-th vf2 covers step j=(64k+lane)/3, channel pair (2r,2r+1)
// with r=(k+lane)%3. Weight a^(-j) advances by a^(-21)/a^(-22) per k
// (select by r) -- no LDS roundtrip, no hexad reshuffle, no exp in loop.
// Final scale a^255; 6-float butterfly at the end.
__global__ __launch_bounds__(256, 8) void k_partials(
    const float* __restrict__ eps0,
    const float* __restrict__ epw,
    float* __restrict__ part)
{
    int lane = threadIdx.x & 63;
    int w = blockIdx.x * 4 + (threadIdx.x >> 6);   // wave-span id
    int b = w / NS, s = w % NS;
    int l0 = s * SPAN;

    const float* rowp = epw + (size_t)b * EPW_ROW;
    int base = 6 * l0 - 6;

    // hoist all 12 coalesced vf2 loads (independent -> one vmcnt wait)
    vf2 v[12];
    #pragma unroll
    for (int k = 0; k < 12; ++k) {
        int idx = base + 2 * (k * 64 + lane);
        int cidx = idx < 0 ? 0 : idx;              // s==0 guard (substituted)
        v[k] = *(const vf2*)(rowp + cidx);
    }
    __builtin_amdgcn_sched_barrier(0);

    const float Am21 = (float)(1.0 / apow(21));    // a^-21
    const float Am22 = (float)(1.0 / apow(22));    // a^-22
    const float A255 = (float)apow(255);

    // seed pair for s==0, lane<3 (j==0 hexad lives in lanes 0..2 at k==0)
    vf2 seed = {0.f, 0.f};
    if (s == 0 && lane < 3) {
        const float* e0 = eps0 + b * NCH;
        float sx = (lane < 2) ? 0.2f : 0.015f;     // c=2*lane
        float sy = (lane < 1) ? 0.2f : 0.015f;     // c=2*lane+1
        seed.x = e0[2 * lane] * sx;
        seed.y = e0[2 * lane + 1] * sy;
    }

    // w = a^(-j0), j0 = lane/3 at k=0 (exact, init-time repeated-squaring)
    float wgt = (float)(1.0 / apow(lane / 3));
    int r3 = lane % 3;

    vf2 a0 = {0.f, 0.f}, a1 = {0.f, 0.f}, a2 = {0.f, 0.f};
    #pragma unroll
    for (int k = 0; k < 12; ++k) {
        vf2 ds;
        ds.x = (r3 == 2) ? DS_GYRO : DS_ACC;       // c=2r
        ds.y = (r3 == 0) ? DS_ACC : DS_GYRO;       // c=2r+1
        vf2 wv = v[k] * ds * wgt;
        if (k == 0 && s == 0 && lane < 3) wv = seed;   // j==0 -> seed (w=1)
        a0 += (r3 == 0) ? wv : (vf2){0.f, 0.f};
        a1 += (r3 == 1) ? wv : (vf2){0.f, 0.f};
        a2 += (r3 == 2) ? wv : (vf2){0.f, 0.f};
        bool c = (r3 == 2);
        wgt *= c ? Am22 : Am21;
        r3 = c ? 0 : r3 + 1;
    }

    // butterfly-sum the 6 accumulator floats across 64 lanes
    float t[6] = {a0.x, a0.y, a1.x, a1.y, a2.x, a2.y};
    #pragma unroll
    for (int c = 0; c < 6; ++c) {
        #pragma unroll
        for (int m = 1; m < 64; m <<= 1) t[c] += __shfl_xor(t[c], m, 64);
    }

    if (lane < 6) {
        float r = t[0];
        if (lane == 1) r = t[1]; else if (lane == 2) r = t[2];
        else if (lane == 3) r = t[3]; else if (lane == 4) r = t[4];
        else if (lane == 5) r = t[5];
        part[(size_t)w * NCH + lane] = r * A255;
    }
}

// ---------- K2: scan span aggregates per chain (tiny, double) ----------
__global__ __launch_bounds__(64) void k_scan(
    const float* __restrict__ part,
    float* __restrict__ carry)
{
    int lane = threadIdx.x;
    int chain = blockIdx.x;              // b*6 + c
    int b = chain / NCH, c = chain % NCH;

    double a = (double)AF;
    double A = a;
    #pragma unroll
    for (int k = 0; k < 8; ++k) A *= A;  // a^256 = a^SPAN
    double A4 = A * A; A4 *= A4;         // A^4 (per-lane span of 4 segments)

    int s0 = lane * 4;
    size_t base = (size_t)b * NS * NCH + c;
    float pv[4];
    #pragma unroll
    for (int k = 0; k < 4; ++k) pv[k] = part[base + (size_t)(s0 + k) * NCH];

    double t = 0.0;
    #pragma unroll
    for (int k = 0; k < 4; ++k) t = A * t + (double)pv[k];

    double I = t, m = A4;
    #pragma unroll
    for (int d = 1; d <= 32; d <<= 1) {
        double up = __shfl_up(I, d, 64);
        if (lane >= d) I = m * up + I;
        m = m * m;
    }
    double cin = __shfl_up(I, 1, 64);
    if (lane == 0) cin = 0.0;

    double e = cin;
    #pragma unroll
    for (int k = 0; k < 4; ++k) {
        carry[base + (size_t)(s0 + k) * NCH] = (float)e;  // E_{s-1}
        e = A * e + (double)pv[k];
    }
}

// ---------- K3: fused scan + elementwise (round-5 version, unchanged) ----------
// One 24KB wave-private tile, reused twice: (A) stage epw coalesced ->
// read x hexads; (E) overwrite with bias hexads -> read float4 -> nt store.
// All same-wave LDS reuse: lgkmcnt-ordered, in-order DS pipe, no barriers.
__global__ __launch_bounds__(256, 4) void k_apply(
    const float* __restrict__ imu,
    const float* __restrict__ eps0,
    const float* __restrict__ epw,
    const float* __restrict__ mn,
    const float* __restrict__ carry,
    float* __restrict__ out)
{
    __shared__ float lds[4 * TILE];                // 24 KB
    int lane = threadIdx.x & 63;
    int wv   = threadIdx.x >> 6;
    int w = blockIdx.x * 4 + wv;
    int b = w / NS, s = w % NS;
    int l0 = s * SPAN;
    float* lw = lds + wv * TILE;

    // ---- phase A: stage epw -> tile (cached loads; L3-resident from K1) ----
    stage_epw(epw + (size_t)b * EPW_ROW, lw, l0);
    __builtin_amdgcn_sched_barrier(0);

    // ---- phase B: carry + imu/mn float4 nt loads, pinned ----
    float e[6];
    #pragma unroll
    for (int c = 0; c < 6; ++c) e[c] = carry[(size_t)w * NCH + c];
    size_t fbase = (size_t)b * ROW + (size_t)l0 * NCH;
    const vf4* ip = (const vf4*)(imu + fbase);
    const vf4* mp = (const vf4*)(mn + fbase);
    vf4 iv[6], mv[6];
    #pragma unroll
    for (int q = 0; q < 6; ++q) {
        iv[q] = __builtin_nontemporal_load(ip + q * 64 + lane);
        mv[q] = __builtin_nontemporal_load(mp + q * 64 + lane);
    }
    __builtin_amdgcn_sched_barrier(0);

    // ---- phase C: VALU while loads fly ----
    float ap1, arev; lane_pows(lane, ap1, arev);
    const float A64 = a_pow64();
    const float inv   = 1.0f / 65535.0f;
    const float twopi = 6.283185307179586f;
    float ta[NIT], tg[NIT];
    #pragma unroll
    for (int it = 0; it < NIT; ++it) {
        int l = l0 + it * 64 + lane;
        float tt = (float)l * inv;
        float temp = fmaf(5.0f, __sinf(twopi * tt), fmaf(2.0f, tt, 20.0f));
        ta[it] = temp * 0.001f; tg[it] = temp * 0.01f;
    }

    // ---- phase D: x from tile, 24 independent Kogge-Stone chains ----
    float x[NIT][6];
    #pragma unroll
    for (int it = 0; it < NIT; ++it) read_x(lw, eps0, b, l0, it, x[it]);

    float m = AF;
    #pragma unroll
    for (int d = 1; d < 64; d <<= 1) {
        #pragma unroll
        for (int it = 0; it < NIT; ++it) {
            #pragma unroll
            for (int c = 0; c < 6; ++c) {
                float up = __shfl_up(x[it][c], d, 64);
                if (lane >= d) x[it][c] = fmaf(m, up, x[it][c]);
            }
        }
        m *= m;
    }

    // carry fixup + fold temp term (per time,ch domain)
    #pragma unroll
    for (int c = 0; c < 6; ++c) {
        float ec = e[c];
        #pragma unroll
        for (int it = 0; it < NIT; ++it) {
            float z = __shfl(x[it][c], 63, 64);
            float t = (c < 3) ? ta[it] : tg[it];
            x[it][c] = fmaf(ap1, ec, x[it][c]) + t;   // bias + temp*tc
            ec = fmaf(A64, ec, z);
        }
    }

    // ---- phase E: overwrite tile with bias hexads ----
    #pragma unroll
    for (int it = 0; it < NIT; ++it) {
        vf2* d = (vf2*)(lw + it * 384 + lane * 6);
        vf2 a0 = {x[it][0], x[it][1]};
        vf2 a1 = {x[it][2], x[it][3]};
        vf2 a2 = {x[it][4], x[it][5]};
        d[0] = a0; d[1] = a1; d[2] = a2;
    }

    // ---- phase F: read tile as float4, combine, full-line nt stores ----
    int lane3 = lane % 3;                     // (q*64+lane)%3 == (q+lane)%3
    vf4* op = (vf4*)(out + fbase);
    const vf4* lr = (const vf4*)lw;
    #pragma unroll
    for (int q = 0; q < 6; ++q) {
        vf4 v = lr[q * 64 + lane];            // lgkmcnt-ordered vs phase E
        int r = lane3 + (q % 3); if (r >= 3) r -= 3;
        vf4 ns = (r == 0) ? (vf4){0.1f, 0.1f, 0.1f, 0.01f}
               : (r == 1) ? (vf4){0.01f, 0.01f, 0.1f, 0.1f}
                          : (vf4){0.1f, 0.01f, 0.01f, 0.01f};
        vf4 o = iv[q] + v + mv[q] * ns;
        __builtin_nontemporal_store(o, op + q * 64 + lane);
    }
}

extern "C" void kernel_launch(void* const* d_in, const int* in_sizes, int n_in,
                              void* d_out, int out_size, void* d_ws, size_t ws_size,
                              hipStream_t stream) {
    const float* imu  = (const float*)d_in[0];   // [B, L, 6]
    const float* eps0 = (const float*)d_in[1];   // [B, 6]
    const float* epw  = (const float*)d_in[2];   // [B, L-1, 6]
    const float* mn   = (const float*)d_in[3];   // [B, L, 6]
    float* out = (float*)d_out;

    float* part  = (float*)d_ws;                 // NWAVE*6 floats
    float* carry = part + (size_t)NWAVE * NCH;   // NWAVE*6 floats

    k_partials<<<NWAVE / 4, 256, 0, stream>>>(eps0, epw, part);
    k_scan<<<Bn * NCH, 64, 0, stream>>>(part, carry);
    k_apply<<<NWAVE / 4, 256, 0, stream>>>(imu, eps0, epw, mn, carry, out);
}

// Round 9
// 177.488 us; speedup vs baseline: 1.0459x; 1.0103x over previous
//
#include <hip/hip_runtime.h>
#include <math.h>

// Problem constants
constexpr int Bn   = 32;
constexpr int L    = 65536;            // T*K
constexpr int NCH  = 6;
constexpr int SPAN = 256;              // hexads (l-steps) per wave-span
constexpr int NS   = L / SPAN;         // 256 spans per batch row
constexpr int NIT  = SPAN / 64;        // 4 blocks of 64 per span
constexpr int ROW  = L * NCH;          // floats per row (imu/mn/out)
constexpr int EPW_ROW = (L - 1) * NCH; // floats per row (eps_walk)
constexpr int NWAVE = Bn * NS;         // 8192 wave-spans
constexpr int TILE = SPAN * NCH;       // 1536 floats per wave tile
constexpr float AF = 0.99999f;         // a = 1 - theta*dt (fp32, matches ref)
constexpr float DS_ACC  = 0.2f   * 0.004472135954999579f; // std*sqrt(2*theta*dt)
constexpr float DS_GYRO = 0.015f * 0.004472135954999579f;

// native clang vectors (HIP float2/float4 are class types -> nontemporal
// builtins reject them)
typedef float vf2 __attribute__((ext_vector_type(2)));
typedef float vf4 __attribute__((ext_vector_type(4)));

// a^(lane+1) and a^(63-lane), double-accurate, computed once per thread
__device__ __forceinline__ void lane_pows(int lane, float& ap1, float& arev) {
    const double a = (double)AF;
    double t = a, p1 = 1.0, pr = 1.0;
    int e1 = lane + 1, er = 63 - lane;
    #pragma unroll
    for (int k = 0; k < 7; ++k) {
        if (e1 & (1 << k)) p1 *= t;
        if (er & (1 << k)) pr *= t;
        t *= t;
    }
    ap1 = (float)p1; arev = (float)pr;
}

__device__ __forceinline__ float a_pow64() {
    double t = (double)AF;
    #pragma unroll
    for (int k = 0; k < 6; ++k) t *= t;   // a^64
    return (float)t;
}

// a^e for 0<=e<512, double repeated-squaring (init-time only)
__device__ __forceinline__ double apow(int e) {
    double t = (double)AF, p = 1.0;
    #pragma unroll
    for (int k = 0; k < 9; ++k) {
        if (e & (1 << k)) p *= t;
        t *= t;
    }
    return p;
}

// Stage this wave-span's epw window into the wave-private LDS tile.
// Window = floats [6*(l0-1), 6*(l0-1)+1536) = 768 vf2 = 12 contiguous
// coalesced vf2 loads per lane. Tile float f <-> epw row float 6*(l0-1)+f,
// so hexad for step l sits at tile offset 6*(l-l0). s==0: idx<0 clamped
// (garbage lands in the l==0 slot, which the eps0 seed overwrites).
__device__ __forceinline__ void stage_epw(const float* __restrict__ rowp,
                                          float* __restrict__ lw,
                                          int l0) {
    int lane = threadIdx.x & 63;
    int base = 6 * l0 - 6;
    #pragma unroll
    for (int k = 0; k < 12; ++k) {
        int idx = base + 2 * (k * 64 + lane);
        int cidx = idx < 0 ? 0 : idx;     // s==0 guard (seed overwrites)
        vf2 v = *(const vf2*)(rowp + cidx);
        *(vf2*)(lw + 2 * (k * 64 + lane)) = v;
    }
}

// read hexad for block-step (it,lane) from the tile, apply diff scales + seed
__device__ __forceinline__ void read_x(const float* __restrict__ lw,
                                       const float* __restrict__ eps0,
                                       int b, int l0, int it, float x[6]) {
    int lane = threadIdx.x & 63;
    int off = 6 * (it * 64 + lane);
    vf2 v0 = *(const vf2*)(lw + off);
    vf2 v1 = *(const vf2*)(lw + off + 2);
    vf2 v2 = *(const vf2*)(lw + off + 4);
    x[0] = v0.x * DS_ACC;  x[1] = v0.y * DS_ACC;  x[2] = v1.x * DS_ACC;
    x[3] = v1.y * DS_GYRO; x[4] = v2.x * DS_GYRO; x[5] = v2.y * DS_GYRO;
    if (l0 + it * 64 + lane == 0) {       // bias0 seed = eps0*std0
        const float* e0 = eps0 + b * NCH;
        x[0] = e0[0] * 0.2f;   x[1] = e0[1] * 0.2f;   x[2] = e0[2] * 0.2f;
        x[3] = e0[3] * 0.015f; x[4] = e0[4] * 0.015f; x[5] = e0[5] * 0.015f;
    }
}

// ---------- K1: per-span weighted aggregates, STREAMING (no LDS) ----------
// (unchanged from round 8)
__global__ __launch_bounds__(256, 8) void k_partials(
    const float* __restrict__ eps0,
    const float* __restrict__ epw,
    float* __restrict__ part)
{
    int lane = threadIdx.x & 63;
    int w = blockIdx.x * 4 + (threadIdx.x >> 6);   // wave-span id
    int b = w / NS, s = w % NS;
    int l0 = s * SPAN;

    const float* rowp = epw + (size_t)b * EPW_ROW;
    int base = 6 * l0 - 6;

    // hoist all 12 coalesced vf2 loads (independent -> one vmcnt wait)
    vf2 v[12];
    #pragma unroll
    for (int k = 0; k < 12; ++k) {
        int idx = base + 2 * (k * 64 + lane);
        int cidx = idx < 0 ? 0 : idx;              // s==0 guard (substituted)
        v[k] = *(const vf2*)(rowp + cidx);
    }
    __builtin_amdgcn_sched_barrier(0);

    const float Am21 = (float)(1.0 / apow(21));    // a^-21
    const float Am22 = (float)(1.0 / apow(22));    // a^-22
    const float A255 = (float)apow(255);

    // seed pair for s==0, lane<3 (j==0 hexad lives in lanes 0..2 at k==0)
    vf2 seed = {0.f, 0.f};
    if (s == 0 && lane < 3) {
        const float* e0 = eps0 + b * NCH;
        float sx = (lane < 2) ? 0.2f : 0.015f;     // c=2*lane
        float sy = (lane < 1) ? 0.2f : 0.015f;     // c=2*lane+1
        seed.x = e0[2 * lane] * sx;
        seed.y = e0[2 * lane + 1] * sy;
    }

    // w = a^(-j0), j0 = lane/3 at k=0 (exact, init-time repeated-squaring)
    float wgt = (float)(1.0 / apow(lane / 3));
    int r3 = lane % 3;

    vf2 a0 = {0.f, 0.f}, a1 = {0.f, 0.f}, a2 = {0.f, 0.f};
    #pragma unroll
    for (int k = 0; k < 12; ++k) {
        vf2 ds;
        ds.x = (r3 == 2) ? DS_GYRO : DS_ACC;       // c=2r
        ds.y = (r3 == 0) ? DS_ACC : DS_GYRO;       // c=2r+1
        vf2 wv = v[k] * ds * wgt;
        if (k == 0 && s == 0 && lane < 3) wv = seed;   // j==0 -> seed (w=1)
        a0 += (r3 == 0) ? wv : (vf2){0.f, 0.f};
        a1 += (r3 == 1) ? wv : (vf2){0.f, 0.f};
        a2 += (r3 == 2) ? wv : (vf2){0.f, 0.f};
        bool c = (r3 == 2);
        wgt *= c ? Am22 : Am21;
        r3 = c ? 0 : r3 + 1;
    }

    // butterfly-sum the 6 accumulator floats across 64 lanes
    float t[6] = {a0.x, a0.y, a1.x, a1.y, a2.x, a2.y};
    #pragma unroll
    for (int c = 0; c < 6; ++c) {
        #pragma unroll
        for (int m = 1; m < 64; m <<= 1) t[c] += __shfl_xor(t[c], m, 64);
    }

    if (lane < 6) {
        float r = t[0];
        if (lane == 1) r = t[1]; else if (lane == 2) r = t[2];
        else if (lane == 3) r = t[3]; else if (lane == 4) r = t[4];
        else if (lane == 5) r = t[5];
        part[(size_t)w * NCH + lane] = r * A255;
    }
}

// ---------- K2: scan span aggregates per chain (tiny, double) ----------
__global__ __launch_bounds__(64) void k_scan(
    const float* __restrict__ part,
    float* __restrict__ carry)
{
    int lane = threadIdx.x;
    int chain = blockIdx.x;              // b*6 + c
    int b = chain / NCH, c = chain % NCH;

    double a = (double)AF;
    double A = a;
    #pragma unroll
    for (int k = 0; k < 8; ++k) A *= A;  // a^256 = a^SPAN
    double A4 = A * A; A4 *= A4;         // A^4 (per-lane span of 4 segments)

    int s0 = lane * 4;
    size_t base = (size_t)b * NS * NCH + c;
    float pv[4];
    #pragma unroll
    for (int k = 0; k < 4; ++k) pv[k] = part[base + (size_t)(s0 + k) * NCH];

    double t = 0.0;
    #pragma unroll
    for (int k = 0; k < 4; ++k) t = A * t + (double)pv[k];

    double I = t, m = A4;
    #pragma unroll
    for (int d = 1; d <= 32; d <<= 1) {
        double up = __shfl_up(I, d, 64);
        if (lane >= d) I = m * up + I;
        m = m * m;
    }
    double cin = __shfl_up(I, 1, 64);
    if (lane == 0) cin = 0.0;

    double e = cin;
    #pragma unroll
    for (int k = 0; k < 4; ++k) {
        carry[base + (size_t)(s0 + k) * NCH] = (float)e;  // E_{s-1}
        e = A * e + (double)pv[k];
    }
}

// ---------- K3: fused scan + elementwise ----------
// Round-5 structure, ONE change: mn loads moved from phase B to phase F.
// mv[6] (24 VGPRs) was held across the whole 36-step shuffle scan while
// only consumed at the end; moving it cuts peak pressure -> (256,5) caps
// at 102 VGPR -> 5 waves/SIMD (20/CU, was 16). In phase F the 6 mv loads
// issue together before the combine loop; 20 waves/CU TLP hides them.
__global__ __launch_bounds__(256, 5) void k_apply(
    const float* __restrict__ imu,
    const float* __restrict__ eps0,
    const float* __restrict__ epw,
    const float* __restrict__ mn,
    const float* __restrict__ carry,
    float* __restrict__ out)
{
    __shared__ float lds[4 * TILE];                // 24 KB
    int lane = threadIdx.x & 63;
    int wv   = threadIdx.x >> 6;
    int w = blockIdx.x * 4 + wv;
    int b = w / NS, s = w % NS;
    int l0 = s * SPAN;
    float* lw = lds + wv * TILE;

    // ---- phase A: stage epw -> tile (cached loads; L3-resident from K1) ----
    stage_epw(epw + (size_t)b * EPW_ROW, lw, l0);
    __builtin_amdgcn_sched_barrier(0);

    // ---- phase B: carry + imu float4 nt loads, pinned ----
    float e[6];
    #pragma unroll
    for (int c = 0; c < 6; ++c) e[c] = carry[(size_t)w * NCH + c];
    size_t fbase = (size_t)b * ROW + (size_t)l0 * NCH;
    const vf4* ip = (const vf4*)(imu + fbase);
    vf4 iv[6];
    #pragma unroll
    for (int q = 0; q < 6; ++q)
        iv[q] = __builtin_nontemporal_load(ip + q * 64 + lane);
    __builtin_amdgcn_sched_barrier(0);

    // ---- phase C: VALU while loads fly ----
    float ap1, arev; lane_pows(lane, ap1, arev);
    const float A64 = a_pow64();
    const float inv   = 1.0f / 65535.0f;
    const float twopi = 6.283185307179586f;
    float ta[NIT], tg[NIT];
    #pragma unroll
    for (int it = 0; it < NIT; ++it) {
        int l = l0 + it * 64 + lane;
        float tt = (float)l * inv;
        float temp = fmaf(5.0f, __sinf(twopi * tt), fmaf(2.0f, tt, 20.0f));
        ta[it] = temp * 0.001f; tg[it] = temp * 0.01f;
    }

    // ---- phase D: x from tile, 24 independent Kogge-Stone chains ----
    float x[NIT][6];
    #pragma unroll
    for (int it = 0; it < NIT; ++it) read_x(lw, eps0, b, l0, it, x[it]);

    float m = AF;
    #pragma unroll
    for (int d = 1; d < 64; d <<= 1) {
        #pragma unroll
        for (int it = 0; it < NIT; ++it) {
            #pragma unroll
            for (int c = 0; c < 6; ++c) {
                float up = __shfl_up(x[it][c], d, 64);
                if (lane >= d) x[it][c] = fmaf(m, up, x[it][c]);
            }
        }
        m *= m;
    }

    // carry fixup + fold temp term (per time,ch domain)
    #pragma unroll
    for (int c = 0; c < 6; ++c) {
        float ec = e[c];
        #pragma unroll
        for (int it = 0; it < NIT; ++it) {
            float z = __shfl(x[it][c], 63, 64);
            float t = (c < 3) ? ta[it] : tg[it];
            x[it][c] = fmaf(ap1, ec, x[it][c]) + t;   // bias + temp*tc
            ec = fmaf(A64, ec, z);
        }
    }

    // ---- phase E: overwrite tile with bias hexads ----
    #pragma unroll
    for (int it = 0; it < NIT; ++it) {
        vf2* d = (vf2*)(lw + it * 384 + lane * 6);
        vf2 a0 = {x[it][0], x[it][1]};
        vf2 a1 = {x[it][2], x[it][3]};
        vf2 a2 = {x[it][4], x[it][5]};
        d[0] = a0; d[1] = a1; d[2] = a2;
    }

    // ---- phase F: mn loads (hoisted), tile read as float4, combine, store ----
    const vf4* mp = (const vf4*)(mn + fbase);
    vf4 mv[6];
    #pragma unroll
    for (int q = 0; q < 6; ++q)
        mv[q] = __builtin_nontemporal_load(mp + q * 64 + lane);

    int lane3 = lane % 3;                     // (q*64+lane)%3 == (q+lane)%3
    vf4* op = (vf4*)(out + fbase);
    const vf4* lr = (const vf4*)lw;
    #pragma unroll
    for (int q = 0; q < 6; ++q) {
        vf4 v = lr[q * 64 + lane];            // lgkmcnt-ordered vs phase E
        int r = lane3 + (q % 3); if (r >= 3) r -= 3;
        vf4 ns = (r == 0) ? (vf4){0.1f, 0.1f, 0.1f, 0.01f}
               : (r == 1) ? (vf4){0.01f, 0.01f, 0.1f, 0.1f}
                          : (vf4){0.1f, 0.01f, 0.01f, 0.01f};
        vf4 o = iv[q] + v + mv[q] * ns;
        __builtin_nontemporal_store(o, op + q * 64 + lane);
    }
}

extern "C" void kernel_launch(void* const* d_in, const int* in_sizes, int n_in,
                              void* d_out, int out_size, void* d_ws, size_t ws_size,
                              hipStream_t stream) {
    const float* imu  = (const float*)d_in[0];   // [B, L, 6]
    const float* eps0 = (const float*)d_in[1];   // [B, 6]
    const float* epw  = (const float*)d_in[2];   // [B, L-1, 6]
    const float* mn   = (const float*)d_in[3];   // [B, L, 6]
    float* out = (float*)d_out;

    float* part  = (float*)d_ws;                 // NWAVE*6 floats
    float* carry = part + (size_t)NWAVE * NCH;   // NWAVE*6 floats

    k_partials<<<NWAVE / 4, 256, 0, stream>>>(eps0, epw, part);
    k_scan<<<Bn * NCH, 64, 0, stream>>>(part, carry);
    k_apply<<<NWAVE / 4, 256, 0, stream>>>(imu, eps0, epw, mn, carry, out);
}